// Round 3
// baseline (476.213 us; speedup 1.0000x reference)
//
#include <hip/hip_runtime.h>

// Problem constants (match reference setup_inputs / module constants)
#define BB 16
#define LL 4096
#define GG 256
#define RR 84
#define WW 169      // 2*R+1
#define DD 12
#define VOCAB 25    // 2*D+1

// Output element offsets (int32 elements, concat in return order)
#define S_L2L (BB * LL * WW)   // 11,075,584
#define S_G2G (BB * GG * GG)   //  1,048,576
#define S_L2G (BB * LL * GG)   // 16,777,216
#define S_G2L (BB * GG * LL)   // 16,777,216
#define OFF0 0
#define OFF1 (OFF0 + S_L2L)
#define OFF2 (OFF1 + S_G2G)
#define OFF3 (OFF2 + S_L2G)
#define OFF4 (OFF3 + S_G2L)
#define OFF5 (OFF4 + S_L2L)
#define OFF6 (OFF5 + S_G2G)
#define OFF7 (OFF6 + S_L2G)

// Fused writer: 8 elements (2×int4) per thread per stream, 256 threads/block
#define NB_L2L (S_L2L / 2048)   //  5408
#define NB_G2G (S_G2G / 2048)   //   512
#define NB_L2G (S_L2G / 2048)   //  8192
#define NB_G2L (S_G2L / 2048)   //  8192
#define NB_TOTAL (NB_L2L + NB_G2G + NB_L2G + NB_G2L)  // 22304

typedef int v4i __attribute__((ext_vector_type(4)));

static __device__ __forceinline__ void st_nt(int* p, int a, int b, int c, int d) {
    v4i v = {a, b, c, d};
    __builtin_nontemporal_store(v, (v4i*)p);
}

// -------- scan kernel: one block (256 threads) per batch --------
// Produces long_seg (suffix cumsum), glob_seg, and per-(b,i) l2l mask
// interval [klo,khi] via binary search on the non-increasing seg row.
__global__ void scan_kernel(const int* __restrict__ long_bp,
                            const int* __restrict__ glob_bp,
                            int* __restrict__ long_seg,
                            int* __restrict__ glob_seg,
                            int2* __restrict__ lims) {
    const int b = blockIdx.x;
    const int t = threadIdx.x;  // 256 threads
    __shared__ int part[256];
    __shared__ int srow[LL];    // 16 KB: this batch's long_seg row

    // ---- long: 4096 elems, 16 per thread ----
    const int* bp = long_bp + b * LL;
    int vals[16];
    int s = 0;
#pragma unroll
    for (int j = 0; j < 16; ++j) { vals[j] = bp[t * 16 + j]; s += vals[j]; }
    part[t] = s;
    __syncthreads();
    for (int off = 1; off < 256; off <<= 1) {
        int v = (t >= off) ? part[t - off] : 0;
        __syncthreads();
        part[t] += v;
        __syncthreads();
    }
    const int total = part[255];
    int run = (t == 0) ? 0 : part[t - 1];   // exclusive prefix at chunk start
    int* seg = long_seg + b * LL;
#pragma unroll
    for (int j = 0; j < 16; ++j) {
        const int v = total - run;          // suffix sum incl. element
        seg[t * 16 + j] = v;
        srow[t * 16 + j] = v;
        run += vals[j];
    }
    __syncthreads();

    // ---- per-i equal-run interval -> l2l mask interval [klo,khi] ----
#pragma unroll 1
    for (int j = 0; j < 16; ++j) {
        const int i = t * 16 + j;
        const int v = srow[i];
        // lo: first idx in [0,i] with srow[idx] <= v  (row is non-increasing)
        int l = 0, h = i;
        while (l < h) { const int mid = (l + h) >> 1; if (srow[mid] <= v) h = mid; else l = mid + 1; }
        const int lo = l;
        // hi: last idx with srow[idx] >= v  == (first idx > i with srow < v) - 1
        l = i + 1; h = LL;
        while (l < h) { const int mid = (l + h) >> 1; if (srow[mid] < v) h = mid; else l = mid + 1; }
        const int hi = l - 1;
        lims[b * LL + i] = make_int2(lo - i + RR, hi - i + RR);
    }
    __syncthreads();

    // ---- glob: 256 elems, 1 per thread ----
    const int gv = glob_bp[b * GG + t];
    part[t] = gv;
    __syncthreads();
    for (int off = 1; off < 256; off <<= 1) {
        int v = (t >= off) ? part[t - off] : 0;
        __syncthreads();
        part[t] += v;
        __syncthreads();
    }
    const int gtot = part[255];
    const int gexcl = (t == 0) ? 0 : part[t - 1];
    glob_seg[b * GG + t] = gtot - gexcl;
}

static __device__ __forceinline__ int rel_of_k(int k) {
    int c = k - RR;
    c = c < -DD ? -DD : (c > DD ? DD : c);
    return (c >= 0) ? c : (DD - c);
}

// -------- fused writer: all 4 (mask, rel) pairs, nt int4 stores --------
__global__ __launch_bounds__(256) void fused_writer(
        const int* __restrict__ long_seg,
        const int* __restrict__ long_pid,
        const int* __restrict__ glob_seg,
        const int2* __restrict__ lims,
        int* __restrict__ out) {
    const int blk = blockIdx.x;
    const int tid = threadIdx.x;

    if (blk < NB_L2L) {
        // ---- l2l: flat f = (b*L + i)*169 + k, 8 elems per thread ----
        const unsigned f = ((unsigned)blk * 256u + (unsigned)tid) * 8u;
        const unsigned row0 = f / (unsigned)WW;
        const int k0 = (int)(f - row0 * (unsigned)WW);
        int m[8], r[8];
        if (k0 <= WW - 8) {
            // all 8 elems in one row
            const int2 lm = lims[row0];
#pragma unroll
            for (int e = 0; e < 8; ++e) {
                const int ke = k0 + e;
                m[e] = (ke >= lm.x && ke <= lm.y) ? 1 : 0;
                r[e] = rel_of_k(ke);
            }
        } else {
#pragma unroll
            for (int e = 0; e < 8; ++e) {
                const unsigned fe = f + (unsigned)e;
                const unsigned rowe = fe / (unsigned)WW;
                const int ke = (int)(fe - rowe * (unsigned)WW);
                const int2 lm = lims[rowe];
                m[e] = (ke >= lm.x && ke <= lm.y) ? 1 : 0;
                r[e] = rel_of_k(ke);
            }
        }
        st_nt(out + OFF0 + f,     m[0], m[1], m[2], m[3]);
        st_nt(out + OFF0 + f + 4, m[4], m[5], m[6], m[7]);
        st_nt(out + OFF4 + f,     r[0], r[1], r[2], r[3]);
        st_nt(out + OFF4 + f + 4, r[4], r[5], r[6], r[7]);

    } else if (blk < NB_L2L + NB_G2G) {
        // ---- g2g: flat f = (b*G + g)*G + h, 8|G so never crosses rows ----
        const unsigned f = ((unsigned)(blk - NB_L2L) * 256u + (unsigned)tid) * 8u;
        const unsigned row = f >> 8;              // b*G + g
        const int h0 = (int)(f & (GG - 1));
        const int g = (int)(row & (GG - 1));
        const int segg = glob_seg[row];
        const int tokg = segg > 0 ? 1 : 0;
        const int* hp = glob_seg + (row - (unsigned)g) + (unsigned)h0;
        const int4 sa = *(const int4*)hp;
        const int4 sb = *(const int4*)(hp + 4);
        const int sh[8] = {sa.x, sa.y, sa.z, sa.w, sb.x, sb.y, sb.z, sb.w};
        int m[8], r[8];
#pragma unroll
        for (int e = 0; e < 8; ++e) {
            const int tokh = sh[e] > 0 ? 1 : 0;
            m[e] = (tokg == tokh) ? 1 : 0;
            r[e] = (segg == sh[e]) ? rel_of_k(h0 + e - g + RR) : (VOCAB + 2);
        }
        st_nt(out + OFF1 + f,     m[0], m[1], m[2], m[3]);
        st_nt(out + OFF1 + f + 4, m[4], m[5], m[6], m[7]);
        st_nt(out + OFF5 + f,     r[0], r[1], r[2], r[3]);
        st_nt(out + OFF5 + f + 4, r[4], r[5], r[6], r[7]);

    } else if (blk < NB_L2L + NB_G2G + NB_L2G) {
        // ---- l2g: flat f = (b*L + i)*G + g ----
        const unsigned f = ((unsigned)(blk - NB_L2L - NB_G2G) * 256u + (unsigned)tid) * 8u;
        const unsigned row = f >> 8;              // b*L + i
        const int g0 = (int)(f & (GG - 1));
        const int b = (int)(row >> 12);
        const int tokl = long_seg[row] > 0 ? 1 : 0;
        const int pid = long_pid[row];
        const int* gp = glob_seg + b * GG + g0;
        const int4 sa = *(const int4*)gp;
        const int4 sb = *(const int4*)(gp + 4);
        const int sg[8] = {sa.x, sa.y, sa.z, sa.w, sb.x, sb.y, sb.z, sb.w};
        int m[8], r[8];
#pragma unroll
        for (int e = 0; e < 8; ++e) {
            const int tokg = sg[e] > 0 ? 1 : 0;
            const int eq = (pid == (g0 + e)) ? 1 : 0;
            m[e] = (tokl == tokg) ? eq : 0;
            r[e] = eq + VOCAB;
        }
        st_nt(out + OFF2 + f,     m[0], m[1], m[2], m[3]);
        st_nt(out + OFF2 + f + 4, m[4], m[5], m[6], m[7]);
        st_nt(out + OFF6 + f,     r[0], r[1], r[2], r[3]);
        st_nt(out + OFF6 + f + 4, r[4], r[5], r[6], r[7]);

    } else {
        // ---- g2l: flat f = (b*G + g)*L + i ----
        const unsigned f = ((unsigned)(blk - NB_L2L - NB_G2G - NB_L2G) * 256u + (unsigned)tid) * 8u;
        const unsigned row = f >> 12;             // b*G + g
        const int i0 = (int)(f & (LL - 1));
        const int g = (int)(row & (GG - 1));
        const int b = (int)(row >> 8);
        const int tokg = glob_seg[row] > 0 ? 1 : 0;
        const int gz = (g == 0) ? 1 : 0;
        const int* pp = long_pid + b * LL + i0;
        const int* sp = long_seg + b * LL + i0;
        const int4 p0 = *(const int4*)pp;
        const int4 p1 = *(const int4*)(pp + 4);
        const int4 s0 = *(const int4*)sp;
        const int4 s1 = *(const int4*)(sp + 4);
        const int pv[8] = {p0.x, p0.y, p0.z, p0.w, p1.x, p1.y, p1.z, p1.w};
        const int sv[8] = {s0.x, s0.y, s0.z, s0.w, s1.x, s1.y, s1.z, s1.w};
        int m[8], r[8];
#pragma unroll
        for (int e = 0; e < 8; ++e) {
            const int tokl = sv[e] > 0 ? 1 : 0;
            const int eq = (g == pv[e]) ? 1 : 0;
            const int allow = eq | gz;
            m[e] = (tokl == tokg) ? allow : 0;
            r[e] = eq + VOCAB;
        }
        st_nt(out + OFF3 + f,     m[0], m[1], m[2], m[3]);
        st_nt(out + OFF3 + f + 4, m[4], m[5], m[6], m[7]);
        st_nt(out + OFF7 + f,     r[0], r[1], r[2], r[3]);
        st_nt(out + OFF7 + f + 4, r[4], r[5], r[6], r[7]);
    }
}

extern "C" void kernel_launch(void* const* d_in, const int* in_sizes, int n_in,
                              void* d_out, int out_size, void* d_ws, size_t ws_size,
                              hipStream_t stream) {
    const int* long_bp  = (const int*)d_in[0];  // (B, L)
    const int* long_pid = (const int*)d_in[1];  // (B, L)
    const int* glob_bp  = (const int*)d_in[2];  // (B, G)
    int* out = (int*)d_out;

    // workspace layout: long_seg (B*L), glob_seg (B*G), lims (B*L int2)
    int*  long_seg = (int*)d_ws;
    int*  glob_seg = long_seg + BB * LL;
    int2* lims     = (int2*)(glob_seg + BB * GG);   // ~803 KB total

    scan_kernel<<<BB, 256, 0, stream>>>(long_bp, glob_bp, long_seg, glob_seg, lims);
    fused_writer<<<NB_TOTAL, 256, 0, stream>>>(long_seg, long_pid, glob_seg, lims, out);
}

// Round 4
// 358.889 us; speedup vs baseline: 1.3269x; 1.3269x over previous
//
#include <hip/hip_runtime.h>

// Problem constants (match reference setup_inputs / module constants)
#define BB 16
#define LL 4096
#define GG 256
#define RR 84
#define WW 169      // 2*R+1
#define DD 12
#define VOCAB 25    // 2*D+1

// Output element offsets (int32 elements, concat in return order)
#define S_L2L (BB * LL * WW)   // 11,075,584
#define S_G2G (BB * GG * GG)   //  1,048,576
#define S_L2G (BB * LL * GG)   // 16,777,216
#define S_G2L (BB * GG * LL)   // 16,777,216
#define OFF0 0
#define OFF1 (OFF0 + S_L2L)
#define OFF2 (OFF1 + S_G2G)
#define OFF3 (OFF2 + S_L2G)
#define OFF4 (OFF3 + S_G2L)
#define OFF5 (OFF4 + S_L2L)
#define OFF6 (OFF5 + S_G2G)
#define OFF7 (OFF6 + S_L2G)

// Fused writer: 1024 elements per block per stream, one int4 per thread per
// stream -> every store instruction is lane-contiguous (1 KB/wave, full lines).
#define NB_L2L (S_L2L / 1024)   // 10816
#define NB_G2G (S_G2G / 1024)   //  1024
#define NB_L2G (S_L2G / 1024)   // 16384
#define NB_G2L (S_G2L / 1024)   // 16384
#define NB_TOTAL (NB_L2L + NB_G2G + NB_L2G + NB_G2L)  // 44608

// -------- suffix-cumsum kernel: one block (256 threads) per batch --------
__global__ void scan_kernel(const int* __restrict__ long_bp,
                            const int* __restrict__ glob_bp,
                            int* __restrict__ long_seg,
                            int* __restrict__ glob_seg) {
    const int b = blockIdx.x;
    const int t = threadIdx.x;  // 256 threads
    __shared__ int part[256];

    // ---- long: 4096 elems, 16 per thread ----
    const int* bp = long_bp + b * LL;
    int vals[16];
    int s = 0;
#pragma unroll
    for (int j = 0; j < 16; ++j) { vals[j] = bp[t * 16 + j]; s += vals[j]; }
    part[t] = s;
    __syncthreads();
    for (int off = 1; off < 256; off <<= 1) {
        int v = (t >= off) ? part[t - off] : 0;
        __syncthreads();
        part[t] += v;
        __syncthreads();
    }
    const int total = part[255];
    int run = (t == 0) ? 0 : part[t - 1];   // exclusive prefix at chunk start
    int* seg = long_seg + b * LL;
#pragma unroll
    for (int j = 0; j < 16; ++j) {
        seg[t * 16 + j] = total - run;      // suffix sum incl. element
        run += vals[j];
    }
    __syncthreads();

    // ---- glob: 256 elems, 1 per thread ----
    const int gv = glob_bp[b * GG + t];
    part[t] = gv;
    __syncthreads();
    for (int off = 1; off < 256; off <<= 1) {
        int v = (t >= off) ? part[t - off] : 0;
        __syncthreads();
        part[t] += v;
        __syncthreads();
    }
    const int gtot = part[255];
    const int gexcl = (t == 0) ? 0 : part[t - 1];
    glob_seg[b * GG + t] = gtot - gexcl;
}

static __device__ __forceinline__ int rel_of_k(int k) {
    int c = k - RR;
    c = c < -DD ? -DD : (c > DD ? DD : c);
    return (c >= 0) ? c : (DD - c);
}

// -------- fused writer: all 4 (mask, rel) pairs, plain int4 stores --------
__global__ __launch_bounds__(256) void fused_writer(
        const int* __restrict__ long_seg,
        const int* __restrict__ long_pid,
        const int* __restrict__ glob_seg,
        int* __restrict__ out) {
    const int blk = blockIdx.x;
    const int tid = threadIdx.x;

    if (blk < NB_L2L) {
        // ---- l2l: flat f = (b*L + i)*169 + k ----
        unsigned f = (unsigned)blk * 1024u + (unsigned)tid * 4u;
        unsigned row = f / (unsigned)WW;          // b*L + i
        int k = (int)(f - row * (unsigned)WW);
        int i = (int)(row & (LL - 1));
        unsigned base = row - (unsigned)i;        // b*L
        int segi = long_seg[row];
        int m[4], r[4];
#pragma unroll
        for (int e = 0; e < 4; ++e) {
            const int j = i + k - RR;
            int msk = 0;
            if (j >= 0 && j < LL) msk = (long_seg[base + (unsigned)j] == segi) ? 1 : 0;
            m[e] = msk;
            r[e] = rel_of_k(k);
            if (e < 3) {
                if (++k == WW) {
                    k = 0; ++row;
                    i = (int)(row & (LL - 1));
                    base = row - (unsigned)i;
                    segi = long_seg[row];
                }
            }
        }
        *(int4*)(out + OFF0 + f) = make_int4(m[0], m[1], m[2], m[3]);
        *(int4*)(out + OFF4 + f) = make_int4(r[0], r[1], r[2], r[3]);

    } else if (blk < NB_L2L + NB_G2G) {
        // ---- g2g: flat f = (b*G + g)*G + h ----
        const unsigned f = (unsigned)(blk - NB_L2L) * 1024u + (unsigned)tid * 4u;
        const unsigned row = f >> 8;              // b*G + g
        const int h0 = (int)(f & (GG - 1));
        const int g = (int)(row & (GG - 1));
        const int segg = glob_seg[row];
        const int tokg = segg > 0 ? 1 : 0;
        const int4 sh = *(const int4*)(glob_seg + (row - (unsigned)g) + (unsigned)h0);
        const int sgh[4] = {sh.x, sh.y, sh.z, sh.w};
        int m[4], r[4];
#pragma unroll
        for (int e = 0; e < 4; ++e) {
            const int tokh = sgh[e] > 0 ? 1 : 0;
            m[e] = (tokg == tokh) ? 1 : 0;
            r[e] = (segg == sgh[e]) ? rel_of_k(h0 + e - g + RR) : (VOCAB + 2);
        }
        *(int4*)(out + OFF1 + f) = make_int4(m[0], m[1], m[2], m[3]);
        *(int4*)(out + OFF5 + f) = make_int4(r[0], r[1], r[2], r[3]);

    } else if (blk < NB_L2L + NB_G2G + NB_L2G) {
        // ---- l2g: flat f = (b*L + i)*G + g ----
        const unsigned f = (unsigned)(blk - NB_L2L - NB_G2G) * 1024u + (unsigned)tid * 4u;
        const unsigned row = f >> 8;              // b*L + i
        const int g0 = (int)(f & (GG - 1));
        const int b = (int)(row >> 12);
        const int tokl = long_seg[row] > 0 ? 1 : 0;
        const int pid = long_pid[row];
        const int4 sg = *(const int4*)(glob_seg + b * GG + g0);
        const int sgv[4] = {sg.x, sg.y, sg.z, sg.w};
        int m[4], r[4];
#pragma unroll
        for (int e = 0; e < 4; ++e) {
            const int tokg = sgv[e] > 0 ? 1 : 0;
            const int eq = (pid == (g0 + e)) ? 1 : 0;
            m[e] = (tokl == tokg) ? eq : 0;
            r[e] = eq + VOCAB;
        }
        *(int4*)(out + OFF2 + f) = make_int4(m[0], m[1], m[2], m[3]);
        *(int4*)(out + OFF6 + f) = make_int4(r[0], r[1], r[2], r[3]);

    } else {
        // ---- g2l: flat f = (b*G + g)*L + i ----
        const unsigned f = (unsigned)(blk - NB_L2L - NB_G2G - NB_L2G) * 1024u + (unsigned)tid * 4u;
        const unsigned row = f >> 12;             // b*G + g
        const int i0 = (int)(f & (LL - 1));
        const int g = (int)(row & (GG - 1));
        const int b = (int)(row >> 8);
        const int tokg = glob_seg[row] > 0 ? 1 : 0;
        const int gz = (g == 0) ? 1 : 0;
        const int4 pid4 = *(const int4*)(long_pid + b * LL + i0);
        const int4 seg4 = *(const int4*)(long_seg + b * LL + i0);
        const int pv[4] = {pid4.x, pid4.y, pid4.z, pid4.w};
        const int sv[4] = {seg4.x, seg4.y, seg4.z, seg4.w};
        int m[4], r[4];
#pragma unroll
        for (int e = 0; e < 4; ++e) {
            const int tokl = sv[e] > 0 ? 1 : 0;
            const int eq = (g == pv[e]) ? 1 : 0;
            const int allow = eq | gz;
            m[e] = (tokl == tokg) ? allow : 0;
            r[e] = eq + VOCAB;
        }
        *(int4*)(out + OFF3 + f) = make_int4(m[0], m[1], m[2], m[3]);
        *(int4*)(out + OFF7 + f) = make_int4(r[0], r[1], r[2], r[3]);
    }
}

extern "C" void kernel_launch(void* const* d_in, const int* in_sizes, int n_in,
                              void* d_out, int out_size, void* d_ws, size_t ws_size,
                              hipStream_t stream) {
    const int* long_bp  = (const int*)d_in[0];  // (B, L)
    const int* long_pid = (const int*)d_in[1];  // (B, L)
    const int* glob_bp  = (const int*)d_in[2];  // (B, G)
    int* out = (int*)d_out;

    // workspace: long_seg (B*L) then glob_seg (B*G) — 278,528 bytes
    int* long_seg = (int*)d_ws;
    int* glob_seg = long_seg + BB * LL;

    scan_kernel<<<BB, 256, 0, stream>>>(long_bp, glob_bp, long_seg, glob_seg);
    fused_writer<<<NB_TOTAL, 256, 0, stream>>>(long_seg, long_pid, glob_seg, out);
}